// Round 4
// baseline (594.211 us; speedup 1.0000x reference)
//
#include <hip/hip_runtime.h>
#include <hip/hip_bf16.h>
#include <stdint.h>

#define T_TOK 4096
#define DIM   2048
#define HID   1024
#define NE    16
#define CAPE  512

typedef __bf16 bf16x8 __attribute__((ext_vector_type(8)));
typedef float  f32x4  __attribute__((ext_vector_type(4)));

__device__ __forceinline__ ushort f2bf(float f) {
    union { float f; uint32_t u; } v; v.f = f;
    uint32_t r = (v.u + 0x7FFFu + ((v.u >> 16) & 1u)) >> 16;
    return (ushort)r;
}
__device__ __forceinline__ float bf2f(ushort u) {
    union { uint32_t u; float f; } v; v.u = (uint32_t)u << 16; return v.f;
}
__device__ __forceinline__ void gload16(const void* g, void* lds) {
    __builtin_amdgcn_global_load_lds(
        (const __attribute__((address_space(1))) uint32_t*)g,
        (__attribute__((address_space(3))) uint32_t*)lds, 16, 0, 0);
}

// ---------------- logits: one wave per token, 18 outputs ----------------
__global__ __launch_bounds__(256) void logits_kernel(
    const float* __restrict__ x, const float* __restrict__ gate_w,
    const float* __restrict__ coef_w, float* __restrict__ logits)
{
    int t = blockIdx.x * 4 + (threadIdx.x >> 6);
    int lane = threadIdx.x & 63;
    const float* xr = x + (size_t)t * DIM;
    float acc[18];
#pragma unroll
    for (int o = 0; o < 18; ++o) acc[o] = 0.f;
    for (int d = lane; d < DIM; d += 64) {
        float xv = xr[d];
        const float* gw = gate_w + (size_t)d * NE;
#pragma unroll
        for (int o = 0; o < NE; ++o) acc[o] += xv * gw[o];
        acc[16] += xv * coef_w[d * 2 + 0];
        acc[17] += xv * coef_w[d * 2 + 1];
    }
#pragma unroll
    for (int off = 32; off > 0; off >>= 1) {
#pragma unroll
        for (int o = 0; o < 18; ++o) acc[o] += __shfl_down(acc[o], off, 64);
    }
    if (lane == 0) {
#pragma unroll
        for (int o = 0; o < 18; ++o) logits[(size_t)t * 18 + o] = acc[o];
    }
}

// ---------------- finish: one thread per token ----------------
__global__ __launch_bounds__(256) void finish_kernel(
    const float* __restrict__ logits, const float* __restrict__ coef_b,
    int* __restrict__ topidx, float* __restrict__ gatesw,
    float* __restrict__ coefo, float* __restrict__ probs_sum)
{
    __shared__ float wred[4][NE];
    int t = blockIdx.x * 256 + threadIdx.x;
    float lg[18];
#pragma unroll
    for (int o = 0; o < 18; ++o) lg[o] = logits[(size_t)t * 18 + o];
    float p[NE];
    float m = lg[0];
#pragma unroll
    for (int e = 1; e < NE; ++e) m = fmaxf(m, lg[e]);
    float ssum = 0.f;
#pragma unroll
    for (int e = 0; e < NE; ++e) { p[e] = expf(lg[e] - m); ssum += p[e]; }
    float inv = 1.f / ssum;
#pragma unroll
    for (int e = 0; e < NE; ++e) p[e] *= inv;
    int i1 = 0;
#pragma unroll
    for (int e = 1; e < NE; ++e) if (p[e] > p[i1]) i1 = e;
    int i2 = -1;
#pragma unroll
    for (int e = 0; e < NE; ++e) { if (e == i1) continue; if (i2 < 0 || p[e] > p[i2]) i2 = e; }
    float g0 = p[i1], g1 = p[i2], gs = g0 + g1;
    topidx[t * 2 + 0] = i1; topidx[t * 2 + 1] = i2;
    gatesw[t * 2 + 0] = g0 / gs; gatesw[t * 2 + 1] = g1 / gs;
    float c0 = lg[16] + coef_b[0], c1 = lg[17] + coef_b[1];
    float cm = fmaxf(c0, c1);
    float e0 = expf(c0 - cm), e1 = expf(c1 - cm);
    float cs = e0 + e1;
    coefo[t * 2 + 0] = e0 / cs; coefo[t * 2 + 1] = e1 / cs;

    float r[NE];
#pragma unroll
    for (int e = 0; e < NE; ++e) r[e] = p[e];
#pragma unroll
    for (int off = 32; off > 0; off >>= 1) {
#pragma unroll
        for (int e = 0; e < NE; ++e) r[e] += __shfl_down(r[e], off, 64);
    }
    int wv = threadIdx.x >> 6, ln = threadIdx.x & 63;
    if (ln == 0) {
#pragma unroll
        for (int e = 0; e < NE; ++e) wred[wv][e] = r[e];
    }
    __syncthreads();
    if (threadIdx.x < NE) {
        float s = wred[0][threadIdx.x] + wred[1][threadIdx.x]
                + wred[2][threadIdx.x] + wred[3][threadIdx.x];
        atomicAdd(&probs_sum[threadIdx.x], s);
    }
}

// ---------------- sequential capacity scan: single block ----------------
__global__ __launch_bounds__(256) void scan_kernel(
    const int* __restrict__ topidx, const float* __restrict__ gatesw,
    const float* __restrict__ probs_sum,
    int* __restrict__ sidx, float* __restrict__ swt,
    int* __restrict__ assign_token, int* __restrict__ nvalid,
    float* __restrict__ out_tail)
{
    __shared__ int run[NE];
    __shared__ int whist[4][NE];
    __shared__ int cnt0[NE];
    __shared__ int base[NE];
    int tid = threadIdx.x, wv = tid >> 6, ln = tid & 63;
    unsigned long long ltmask = (1ull << ln) - 1ull;

    for (int kk = 0; kk < 2; ++kk) {
        if (tid < NE) {
            if (kk == 0) base[tid] = 0;
            else { cnt0[tid] = run[tid]; base[tid] = run[tid]; }
            run[tid] = 0;
        }
        __syncthreads();
        for (int c = 0; c < T_TOK; c += 256) {
            int t = c + tid;
            int e = topidx[t * 2 + kk];
            int within = 0;
            for (int ee = 0; ee < NE; ++ee) {
                unsigned long long b = __ballot(e == ee);
                if (ee == e) within = __popcll(b & ltmask);
                if (ln == 0) whist[wv][ee] = __popcll(b);
            }
            __syncthreads();
            int cross = 0;
            for (int w = 0; w < wv; ++w) cross += whist[w][e];
            int loc = run[e] + cross + within;
            int pos = base[e] + loc;
            bool keep = pos < CAPE;
            sidx[t * 2 + kk] = keep ? (e * CAPE + pos) : -1;
            swt[t * 2 + kk] = keep ? gatesw[t * 2 + kk] : 0.f;
            if (keep) assign_token[e * CAPE + pos] = t;
            __syncthreads();
            if (tid < NE) {
                run[tid] += whist[0][tid] + whist[1][tid] + whist[2][tid] + whist[3][tid];
            }
            __syncthreads();
        }
    }
    if (tid < NE) {
        int c0v = cnt0[tid], c1v = run[tid];
        nvalid[tid] = min(CAPE, c0v + c1v);
        out_tail[1 + tid] = (float)(c0v + c1v);
    }
    __syncthreads();
    if (tid == 0) {
        float la = 0.f;
        for (int e = 0; e < NE; ++e)
            la += (probs_sum[e] / (float)T_TOK) * ((float)cnt0[e] / (float)T_TOK);
        out_tail[0] = la * (float)NE;
    }
}

// ---------------- transpose + convert: f32 [R][C] -> bf16 [C][R] ----------------
__global__ __launch_bounds__(256) void transpose_kernel(
    const float* __restrict__ in, ushort* __restrict__ out,
    int R, int C, size_t IEs, size_t OEs)
{
    __shared__ __align__(16) ushort tile[64][72];
    int e = blockIdx.z;
    const float* ie = in + (size_t)e * IEs;
    ushort* oe = out + (size_t)e * OEs;
    int r0 = blockIdx.x * 64, c0 = blockIdx.y * 64;
    int tid = threadIdx.x;
    int rr = tid >> 4, cc = (tid & 15) * 4;
#pragma unroll
    for (int i = 0; i < 4; ++i) {
        int r = i * 16 + rr;
        float4 v = *(const float4*)(ie + (size_t)(r0 + r) * C + c0 + cc);
        tile[cc + 0][r] = f2bf(v.x);
        tile[cc + 1][r] = f2bf(v.y);
        tile[cc + 2][r] = f2bf(v.z);
        tile[cc + 3][r] = f2bf(v.w);
    }
    __syncthreads();
    int oc = tid >> 3, orr = (tid & 7) * 8;
#pragma unroll
    for (int i = 0; i < 2; ++i) {
        int c = i * 32 + oc;
        uint4 v = *(const uint4*)&tile[c][orr];
        *(uint4*)(oe + (size_t)(c0 + c) * R + r0 + orr) = v;
    }
}

// ---------------- f32 -> bf16 convert (contiguous) ----------------
__global__ __launch_bounds__(256) void convert_kernel(
    const float* __restrict__ in, ushort* __restrict__ out)
{
    int i = (blockIdx.x * 256 + threadIdx.x) * 8;
    float4 a = *(const float4*)(in + i);
    float4 b = *(const float4*)(in + i + 4);
    ushort o[8];
    o[0] = f2bf(a.x); o[1] = f2bf(a.y); o[2] = f2bf(a.z); o[3] = f2bf(a.w);
    o[4] = f2bf(b.x); o[5] = f2bf(b.y); o[6] = f2bf(b.z); o[7] = f2bf(b.w);
    *(uint4*)(out + i) = *(uint4*)o;
}

// ---------------- gather tokens -> dense bf16 [E*CAPE][DIM], zero-fill ----------------
__global__ __launch_bounds__(256) void gather_kernel(
    const float* __restrict__ x, const int* __restrict__ assign_token,
    const int* __restrict__ nvalid, ushort* __restrict__ xg)
{
    int slot = blockIdx.x;
    int e = slot >> 9, c = slot & (CAPE - 1);
    int tid = threadIdx.x;
    ushort o[8];
    if (c < nvalid[e]) {
        int tok = assign_token[slot];
        const float* src = x + (size_t)tok * DIM + tid * 8;
        float4 a = *(const float4*)src;
        float4 b = *(const float4*)(src + 4);
        o[0] = f2bf(a.x); o[1] = f2bf(a.y); o[2] = f2bf(a.z); o[3] = f2bf(a.w);
        o[4] = f2bf(b.x); o[5] = f2bf(b.y); o[6] = f2bf(b.z); o[7] = f2bf(b.w);
    } else {
#pragma unroll
        for (int j = 0; j < 8; ++j) o[j] = 0;
    }
    *(uint4*)(xg + (size_t)slot * DIM + tid * 8) = *(uint4*)o;
}

// ---------------- fused dual GEMM: H = silu(A@B1^T) * (A@B3^T), bf16 out ----------------
// A: [M][K] bf16, B1/B3: [N][K] bf16, H: [M][N] bf16
__global__ __launch_bounds__(256) void gemm13(
    const ushort* __restrict__ A, const ushort* __restrict__ B1,
    const ushort* __restrict__ B3, ushort* __restrict__ H,
    int K, int N,
    size_t Aes, size_t Bes, size_t Hes,
    const int* __restrict__ nvalid)
{
    int e = blockIdx.z;
    int bm = blockIdx.x * 128, bn = blockIdx.y * 128;
    if (nvalid && bm >= nvalid[e]) return;
    const ushort* Ae  = A  + (size_t)e * Aes;
    const ushort* B1e = B1 + (size_t)e * Bes;
    const ushort* B3e = B3 + (size_t)e * Bes;

    __shared__ __align__(16) ushort As[128 * 64];
    __shared__ __align__(16) ushort B1s[128 * 64];
    __shared__ __align__(16) ushort B3s[128 * 64];

    int tid = threadIdx.x;
    int lane = tid & 63;
    int wr = (tid >> 7) & 1;
    int wc = (tid >> 6) & 1;

    f32x4 acc1[4][4], acc3[4][4];
#pragma unroll
    for (int m = 0; m < 4; ++m)
#pragma unroll
        for (int n = 0; n < 4; ++n) {
            acc1[m][n] = (f32x4){0.f, 0.f, 0.f, 0.f};
            acc3[m][n] = (f32x4){0.f, 0.f, 0.f, 0.f};
        }

    for (int k0 = 0; k0 < K; k0 += 64) {
#pragma unroll
        for (int j = 0; j < 4; ++j) {
            int c = j * 256 + tid;
            int r = c >> 3, ce = (c & 7) * 8;
            gload16(Ae + (size_t)(bm + r) * K + k0 + ce, &As[(c - lane) * 8]);
        }
#pragma unroll
        for (int j = 0; j < 4; ++j) {
            int c = j * 256 + tid;
            int r = c >> 3, ce = (c & 7) * 8;
            gload16(B1e + (size_t)(bn + r) * K + k0 + ce, &B1s[(c - lane) * 8]);
        }
#pragma unroll
        for (int j = 0; j < 4; ++j) {
            int c = j * 256 + tid;
            int r = c >> 3, ce = (c & 7) * 8;
            gload16(B3e + (size_t)(bn + r) * K + k0 + ce, &B3s[(c - lane) * 8]);
        }
        __syncthreads();
#pragma unroll
        for (int ks = 0; ks < 2; ++ks) {
            int kb = ks * 32 + (lane >> 4) * 8;
            bf16x8 a[4], b[4];
#pragma unroll
            for (int m = 0; m < 4; ++m)
                a[m] = *(const bf16x8*)&As[(wr * 64 + m * 16 + (lane & 15)) * 64 + kb];
#pragma unroll
            for (int n = 0; n < 4; ++n)
                b[n] = *(const bf16x8*)&B1s[(wc * 64 + n * 16 + (lane & 15)) * 64 + kb];
#pragma unroll
            for (int m = 0; m < 4; ++m)
#pragma unroll
                for (int n = 0; n < 4; ++n)
                    acc1[m][n] = __builtin_amdgcn_mfma_f32_16x16x32_bf16(a[m], b[n], acc1[m][n], 0, 0, 0);
#pragma unroll
            for (int n = 0; n < 4; ++n)
                b[n] = *(const bf16x8*)&B3s[(wc * 64 + n * 16 + (lane & 15)) * 64 + kb];
#pragma unroll
            for (int m = 0; m < 4; ++m)
#pragma unroll
                for (int n = 0; n < 4; ++n)
                    acc3[m][n] = __builtin_amdgcn_mfma_f32_16x16x32_bf16(a[m], b[n], acc3[m][n], 0, 0, 0);
        }
        __syncthreads();
    }

    ushort* He = H + (size_t)e * Hes;
    int rbase = bm + wr * 64 + (lane >> 4) * 4;
    int cbase = bn + wc * 64 + (lane & 15);
#pragma unroll
    for (int m = 0; m < 4; ++m) {
#pragma unroll
        for (int n = 0; n < 4; ++n) {
            int col = cbase + n * 16;
#pragma unroll
            for (int r = 0; r < 4; ++r) {
                int row = rbase + m * 16 + r;
                float g = acc1[m][n][r];
                float s = g / (1.f + __expf(-g));
                He[(size_t)row * N + col] = f2bf(s * acc3[m][n][r]);
            }
        }
    }
}

// ---------------- bf16 MFMA GEMM, m97 structure: C = A @ B^T ----------------
// MODE 0: bf16 out; 3: f32 out * rowscale[2*row]
template<int MODE>
__global__ __launch_bounds__(256) void gemm_bt(
    const ushort* __restrict__ A, const ushort* __restrict__ B,
    void* __restrict__ Out, const float* __restrict__ rowscale,
    int K, int outstride,
    size_t Aes, size_t Bes, size_t Oes,
    const int* __restrict__ nvalid)
{
    int e = blockIdx.z;
    int bm = blockIdx.x * 128, bn = blockIdx.y * 128;
    if (nvalid && bm >= nvalid[e]) return;
    const ushort* Ae = A + (size_t)e * Aes;
    const ushort* Be = B + (size_t)e * Bes;

    __shared__ __align__(16) ushort As[128 * 64];
    __shared__ __align__(16) ushort Bs[128 * 64];

    int tid = threadIdx.x;
    int lane = tid & 63;
    int wr = (tid >> 7) & 1;
    int wc = (tid >> 6) & 1;

    f32x4 acc[4][4];
#pragma unroll
    for (int m = 0; m < 4; ++m)
#pragma unroll
        for (int n = 0; n < 4; ++n)
            acc[m][n] = (f32x4){0.f, 0.f, 0.f, 0.f};

    for (int k0 = 0; k0 < K; k0 += 64) {
#pragma unroll
        for (int j = 0; j < 4; ++j) {
            int c = j * 256 + tid;
            int r = c >> 3, ce = (c & 7) * 8;
            gload16(Ae + (size_t)(bm + r) * K + k0 + ce, &As[(c - lane) * 8]);
        }
#pragma unroll
        for (int j = 0; j < 4; ++j) {
            int c = j * 256 + tid;
            int r = c >> 3, ce = (c & 7) * 8;
            gload16(Be + (size_t)(bn + r) * K + k0 + ce, &Bs[(c - lane) * 8]);
        }
        __syncthreads();
#pragma unroll
        for (int ks = 0; ks < 2; ++ks) {
            int kb = ks * 32 + (lane >> 4) * 8;
            bf16x8 a[4], b[4];
#pragma unroll
            for (int m = 0; m < 4; ++m)
                a[m] = *(const bf16x8*)&As[(wr * 64 + m * 16 + (lane & 15)) * 64 + kb];
#pragma unroll
            for (int n = 0; n < 4; ++n)
                b[n] = *(const bf16x8*)&Bs[(wc * 64 + n * 16 + (lane & 15)) * 64 + kb];
#pragma unroll
            for (int m = 0; m < 4; ++m)
#pragma unroll
                for (int n = 0; n < 4; ++n)
                    acc[m][n] = __builtin_amdgcn_mfma_f32_16x16x32_bf16(a[m], b[n], acc[m][n], 0, 0, 0);
        }
        __syncthreads();
    }

    ushort* Ob = (ushort*)Out + (size_t)e * Oes;
    float*  Of = (float*)Out + (size_t)e * Oes;
    int rbase = bm + wr * 64 + (lane >> 4) * 4;
    int cbase = bn + wc * 64 + (lane & 15);
#pragma unroll
    for (int m = 0; m < 4; ++m) {
#pragma unroll
        for (int n = 0; n < 4; ++n) {
            int col = cbase + n * 16;
#pragma unroll
            for (int r = 0; r < 4; ++r) {
                int row = rbase + m * 16 + r;
                float v = acc[m][n][r];
                if (MODE == 0) {
                    Ob[(size_t)row * outstride + col] = f2bf(v);
                } else {
                    Of[(size_t)row * outstride + col] = v * rowscale[2 * row];
                }
            }
        }
    }
}

// ---------------- final combine: out += coef0*(w0*ye[s0] + w1*ye[s1]) ----------------
__global__ __launch_bounds__(256) void combine_kernel(
    const ushort* __restrict__ ye, const int* __restrict__ sidx,
    const float* __restrict__ swt, const float* __restrict__ coefo,
    float* __restrict__ out)
{
    int idx = blockIdx.x * 256 + threadIdx.x;
    int t = idx >> 9;
    int d = (idx & 511) << 2;
    int s0 = sidx[t * 2], s1 = sidx[t * 2 + 1];
    float c0 = coefo[t * 2];
    float w0 = swt[t * 2] * c0, w1 = swt[t * 2 + 1] * c0;
    float4 v = *(float4*)(out + (size_t)t * DIM + d);
    if (s0 >= 0) {
        const ushort* y = ye + (size_t)s0 * DIM + d;
        v.x += w0 * bf2f(y[0]); v.y += w0 * bf2f(y[1]);
        v.z += w0 * bf2f(y[2]); v.w += w0 * bf2f(y[3]);
    }
    if (s1 >= 0) {
        const ushort* y = ye + (size_t)s1 * DIM + d;
        v.x += w1 * bf2f(y[0]); v.y += w1 * bf2f(y[1]);
        v.z += w1 * bf2f(y[2]); v.w += w1 * bf2f(y[3]);
    }
    *(float4*)(out + (size_t)t * DIM + d) = v;
}

extern "C" void kernel_launch(void* const* d_in, const int* in_sizes, int n_in,
                              void* d_out, int out_size, void* d_ws, size_t ws_size,
                              hipStream_t stream)
{
    const float* x      = (const float*)d_in[0];
    const float* gate_w = (const float*)d_in[1];
    const float* w1     = (const float*)d_in[2];
    const float* w3     = (const float*)d_in[3];
    const float* w2     = (const float*)d_in[4];
    const float* sw1    = (const float*)d_in[5];
    const float* sw3    = (const float*)d_in[6];
    const float* sw2    = (const float*)d_in[7];
    const float* coef_w = (const float*)d_in[8];
    const float* coef_b = (const float*)d_in[9];
    float* out = (float*)d_out;

    char* ws = (char*)d_ws;
    size_t off = 0;
    auto alloc = [&](size_t bytes) -> void* {
        void* p = ws + off;
        off += (bytes + 255) & ~(size_t)255;
        return p;
    };
    float*  probs_sum    = (float*)alloc(NE * 4);
    int*    nvalid       = (int*)alloc(NE * 4);
    int*    topidx       = (int*)alloc((size_t)T_TOK * 2 * 4);
    float*  gatesw       = (float*)alloc((size_t)T_TOK * 2 * 4);
    float*  coefo        = (float*)alloc((size_t)T_TOK * 2 * 4);
    int*    sidx         = (int*)alloc((size_t)T_TOK * 2 * 4);
    float*  swt          = (float*)alloc((size_t)T_TOK * 2 * 4);
    int*    assign_token = (int*)alloc((size_t)NE * CAPE * 4);
    float*  logits       = (float*)alloc((size_t)T_TOK * 18 * 4);
    ushort* w1T  = (ushort*)alloc((size_t)NE * HID * DIM * 2);
    ushort* w3T  = (ushort*)alloc((size_t)NE * HID * DIM * 2);
    ushort* w2T  = (ushort*)alloc((size_t)NE * DIM * HID * 2);
    ushort* sw1T = (ushort*)alloc((size_t)HID * DIM * 2);
    ushort* sw3T = (ushort*)alloc((size_t)HID * DIM * 2);
    ushort* sw2T = (ushort*)alloc((size_t)DIM * HID * 2);
    ushort* xb   = (ushort*)alloc((size_t)T_TOK * DIM * 2);
    ushort* xg   = (ushort*)alloc((size_t)NE * CAPE * DIM * 2);
    ushort* h1   = (ushort*)alloc((size_t)T_TOK * HID * 2);
    ushort* he1  = (ushort*)alloc((size_t)NE * CAPE * HID * 2);
    ushort* ye   = (ushort*)alloc((size_t)NE * CAPE * DIM * 2);

    hipMemsetAsync(probs_sum, 0, NE * 4, stream);
    logits_kernel<<<T_TOK / 4, 256, 0, stream>>>(x, gate_w, coef_w, logits);
    finish_kernel<<<T_TOK / 256, 256, 0, stream>>>(logits, coef_b,
                                                   topidx, gatesw, coefo, probs_sum);
    scan_kernel<<<1, 256, 0, stream>>>(topidx, gatesw, probs_sum,
                                       sidx, swt, assign_token, nvalid,
                                       out + (size_t)T_TOK * DIM);

    // weight transposes + x convert
    transpose_kernel<<<dim3(DIM/64, HID/64, NE), 256, 0, stream>>>(w1, w1T, DIM, HID, (size_t)DIM*HID, (size_t)HID*DIM);
    transpose_kernel<<<dim3(DIM/64, HID/64, NE), 256, 0, stream>>>(w3, w3T, DIM, HID, (size_t)DIM*HID, (size_t)HID*DIM);
    transpose_kernel<<<dim3(HID/64, DIM/64, NE), 256, 0, stream>>>(w2, w2T, HID, DIM, (size_t)HID*DIM, (size_t)DIM*HID);
    transpose_kernel<<<dim3(DIM/64, HID/64, 1), 256, 0, stream>>>(sw1, sw1T, DIM, HID, 0, 0);
    transpose_kernel<<<dim3(DIM/64, HID/64, 1), 256, 0, stream>>>(sw3, sw3T, DIM, HID, 0, 0);
    transpose_kernel<<<dim3(HID/64, DIM/64, 1), 256, 0, stream>>>(sw2, sw2T, HID, DIM, 0, 0);
    convert_kernel<<<(T_TOK * DIM) / (256 * 8), 256, 0, stream>>>(x, xb);
    gather_kernel<<<NE * CAPE, 256, 0, stream>>>(x, assign_token, nvalid, xg);

    // shared MLP: h1 = silu(xb@sw1T)*(xb@sw3T); out = (h1@sw2T)*coef1
    gemm13<<<dim3(T_TOK/128, HID/128, 1), 256, 0, stream>>>(
        xb, sw1T, sw3T, h1, DIM, HID, 0, 0, 0, nullptr);

    // experts: he1 = silu(xg@w1T)*(xg@w3T); ye = he1@w2T (bf16)
    gemm13<<<dim3(CAPE/128, HID/128, NE), 256, 0, stream>>>(
        xg, w1T, w3T, he1, DIM, HID,
        (size_t)CAPE*DIM, (size_t)HID*DIM, (size_t)CAPE*HID, nvalid);
    gemm_bt<0><<<dim3(CAPE/128, DIM/128, NE), 256, 0, stream>>>(
        he1, w2T, ye, nullptr, HID, DIM,
        (size_t)CAPE*HID, (size_t)DIM*HID, (size_t)CAPE*DIM, nvalid);

    gemm_bt<3><<<dim3(T_TOK/128, DIM/128, 1), 256, 0, stream>>>(
        h1, sw2T, out, coefo + 1, HID, DIM, 0, 0, 0, nullptr);

    combine_kernel<<<(T_TOK * (DIM / 4)) / 256, 256, 0, stream>>>(ye, sidx, swt, coefo, out);
}

// Round 5
// 558.277 us; speedup vs baseline: 1.0644x; 1.0644x over previous
//
#include <hip/hip_runtime.h>
#include <hip/hip_bf16.h>
#include <stdint.h>

#define T_TOK 4096
#define DIM   2048
#define HID   1024
#define NE    16
#define CAPE  512

typedef __bf16 bf16x8 __attribute__((ext_vector_type(8)));
typedef float  f32x4  __attribute__((ext_vector_type(4)));

__device__ __forceinline__ ushort f2bf(float f) {
    union { float f; uint32_t u; } v; v.f = f;
    uint32_t r = (v.u + 0x7FFFu + ((v.u >> 16) & 1u)) >> 16;
    return (ushort)r;
}
__device__ __forceinline__ float bf2f(ushort u) {
    union { uint32_t u; float f; } v; v.u = (uint32_t)u << 16; return v.f;
}
__device__ __forceinline__ void gload16(const void* g, void* lds) {
    __builtin_amdgcn_global_load_lds(
        (const __attribute__((address_space(1))) uint32_t*)g,
        (__attribute__((address_space(3))) uint32_t*)lds, 16, 0, 0);
}

// ---------------- logits: one wave per token, 18 outputs ----------------
__global__ __launch_bounds__(256) void logits_kernel(
    const float* __restrict__ x, const float* __restrict__ gate_w,
    const float* __restrict__ coef_w, float* __restrict__ logits)
{
    int t = blockIdx.x * 4 + (threadIdx.x >> 6);
    int lane = threadIdx.x & 63;
    const float* xr = x + (size_t)t * DIM;
    float acc[18];
#pragma unroll
    for (int o = 0; o < 18; ++o) acc[o] = 0.f;
    for (int d = lane; d < DIM; d += 64) {
        float xv = xr[d];
        const float* gw = gate_w + (size_t)d * NE;
#pragma unroll
        for (int o = 0; o < NE; ++o) acc[o] += xv * gw[o];
        acc[16] += xv * coef_w[d * 2 + 0];
        acc[17] += xv * coef_w[d * 2 + 1];
    }
#pragma unroll
    for (int off = 32; off > 0; off >>= 1) {
#pragma unroll
        for (int o = 0; o < 18; ++o) acc[o] += __shfl_down(acc[o], off, 64);
    }
    if (lane == 0) {
#pragma unroll
        for (int o = 0; o < 18; ++o) logits[(size_t)t * 18 + o] = acc[o];
    }
}

// ---------------- finish: one thread per token ----------------
__global__ __launch_bounds__(256) void finish_kernel(
    const float* __restrict__ logits, const float* __restrict__ coef_b,
    int* __restrict__ topidx, float* __restrict__ gatesw,
    float* __restrict__ coefo, float* __restrict__ probs_sum)
{
    __shared__ float wred[4][NE];
    int t = blockIdx.x * 256 + threadIdx.x;
    float lg[18];
#pragma unroll
    for (int o = 0; o < 18; ++o) lg[o] = logits[(size_t)t * 18 + o];
    float p[NE];
    float m = lg[0];
#pragma unroll
    for (int e = 1; e < NE; ++e) m = fmaxf(m, lg[e]);
    float ssum = 0.f;
#pragma unroll
    for (int e = 0; e < NE; ++e) { p[e] = expf(lg[e] - m); ssum += p[e]; }
    float inv = 1.f / ssum;
#pragma unroll
    for (int e = 0; e < NE; ++e) p[e] *= inv;
    int i1 = 0;
#pragma unroll
    for (int e = 1; e < NE; ++e) if (p[e] > p[i1]) i1 = e;
    int i2 = -1;
#pragma unroll
    for (int e = 0; e < NE; ++e) { if (e == i1) continue; if (i2 < 0 || p[e] > p[i2]) i2 = e; }
    float g0 = p[i1], g1 = p[i2], gs = g0 + g1;
    topidx[t * 2 + 0] = i1; topidx[t * 2 + 1] = i2;
    gatesw[t * 2 + 0] = g0 / gs; gatesw[t * 2 + 1] = g1 / gs;
    float c0 = lg[16] + coef_b[0], c1 = lg[17] + coef_b[1];
    float cm = fmaxf(c0, c1);
    float e0 = expf(c0 - cm), e1 = expf(c1 - cm);
    float cs = e0 + e1;
    coefo[t * 2 + 0] = e0 / cs; coefo[t * 2 + 1] = e1 / cs;

    float r[NE];
#pragma unroll
    for (int e = 0; e < NE; ++e) r[e] = p[e];
#pragma unroll
    for (int off = 32; off > 0; off >>= 1) {
#pragma unroll
        for (int e = 0; e < NE; ++e) r[e] += __shfl_down(r[e], off, 64);
    }
    int wv = threadIdx.x >> 6, ln = threadIdx.x & 63;
    if (ln == 0) {
#pragma unroll
        for (int e = 0; e < NE; ++e) wred[wv][e] = r[e];
    }
    __syncthreads();
    if (threadIdx.x < NE) {
        float s = wred[0][threadIdx.x] + wred[1][threadIdx.x]
                + wred[2][threadIdx.x] + wred[3][threadIdx.x];
        atomicAdd(&probs_sum[threadIdx.x], s);
    }
}

// ---------------- sequential capacity scan: single block ----------------
__global__ __launch_bounds__(256) void scan_kernel(
    const int* __restrict__ topidx, const float* __restrict__ gatesw,
    const float* __restrict__ probs_sum,
    int* __restrict__ sidx, float* __restrict__ swt,
    int* __restrict__ assign_token, int* __restrict__ nvalid,
    float* __restrict__ out_tail)
{
    __shared__ int run[NE];
    __shared__ int whist[4][NE];
    __shared__ int cnt0[NE];
    __shared__ int base[NE];
    int tid = threadIdx.x, wv = tid >> 6, ln = tid & 63;
    unsigned long long ltmask = (1ull << ln) - 1ull;

    for (int kk = 0; kk < 2; ++kk) {
        if (tid < NE) {
            if (kk == 0) base[tid] = 0;
            else { cnt0[tid] = run[tid]; base[tid] = run[tid]; }
            run[tid] = 0;
        }
        __syncthreads();
        for (int c = 0; c < T_TOK; c += 256) {
            int t = c + tid;
            int e = topidx[t * 2 + kk];
            int within = 0;
            for (int ee = 0; ee < NE; ++ee) {
                unsigned long long b = __ballot(e == ee);
                if (ee == e) within = __popcll(b & ltmask);
                if (ln == 0) whist[wv][ee] = __popcll(b);
            }
            __syncthreads();
            int cross = 0;
            for (int w = 0; w < wv; ++w) cross += whist[w][e];
            int loc = run[e] + cross + within;
            int pos = base[e] + loc;
            bool keep = pos < CAPE;
            sidx[t * 2 + kk] = keep ? (e * CAPE + pos) : -1;
            swt[t * 2 + kk] = keep ? gatesw[t * 2 + kk] : 0.f;
            if (keep) assign_token[e * CAPE + pos] = t;
            __syncthreads();
            if (tid < NE) {
                run[tid] += whist[0][tid] + whist[1][tid] + whist[2][tid] + whist[3][tid];
            }
            __syncthreads();
        }
    }
    if (tid < NE) {
        int c0v = cnt0[tid], c1v = run[tid];
        nvalid[tid] = min(CAPE, c0v + c1v);
        out_tail[1 + tid] = (float)(c0v + c1v);
    }
    __syncthreads();
    if (tid == 0) {
        float la = 0.f;
        for (int e = 0; e < NE; ++e)
            la += (probs_sum[e] / (float)T_TOK) * ((float)cnt0[e] / (float)T_TOK);
        out_tail[0] = la * (float)NE;
    }
}

// ---------------- transpose + convert: f32 [R][C] -> bf16 [C][R] ----------------
__global__ __launch_bounds__(256) void transpose_kernel(
    const float* __restrict__ in, ushort* __restrict__ out,
    int R, int C, size_t IEs, size_t OEs)
{
    __shared__ __align__(16) ushort tile[64][72];
    int e = blockIdx.z;
    const float* ie = in + (size_t)e * IEs;
    ushort* oe = out + (size_t)e * OEs;
    int r0 = blockIdx.x * 64, c0 = blockIdx.y * 64;
    int tid = threadIdx.x;
    int rr = tid >> 4, cc = (tid & 15) * 4;
#pragma unroll
    for (int i = 0; i < 4; ++i) {
        int r = i * 16 + rr;
        float4 v = *(const float4*)(ie + (size_t)(r0 + r) * C + c0 + cc);
        tile[cc + 0][r] = f2bf(v.x);
        tile[cc + 1][r] = f2bf(v.y);
        tile[cc + 2][r] = f2bf(v.z);
        tile[cc + 3][r] = f2bf(v.w);
    }
    __syncthreads();
    int oc = tid >> 3, orr = (tid & 7) * 8;
#pragma unroll
    for (int i = 0; i < 2; ++i) {
        int c = i * 32 + oc;
        uint4 v = *(const uint4*)&tile[c][orr];
        *(uint4*)(oe + (size_t)(c0 + c) * R + r0 + orr) = v;
    }
}

// ---------------- f32 -> bf16 convert (contiguous) ----------------
__global__ __launch_bounds__(256) void convert_kernel(
    const float* __restrict__ in, ushort* __restrict__ out)
{
    int i = (blockIdx.x * 256 + threadIdx.x) * 8;
    float4 a = *(const float4*)(in + i);
    float4 b = *(const float4*)(in + i + 4);
    ushort o[8];
    o[0] = f2bf(a.x); o[1] = f2bf(a.y); o[2] = f2bf(a.z); o[3] = f2bf(a.w);
    o[4] = f2bf(b.x); o[5] = f2bf(b.y); o[6] = f2bf(b.z); o[7] = f2bf(b.w);
    *(uint4*)(out + i) = *(uint4*)o;
}

// ---------------- gather tokens -> dense bf16 [E*CAPE][DIM], zero-fill ----------------
__global__ __launch_bounds__(256) void gather_kernel(
    const float* __restrict__ x, const int* __restrict__ assign_token,
    const int* __restrict__ nvalid, ushort* __restrict__ xg)
{
    int slot = blockIdx.x;
    int e = slot >> 9, c = slot & (CAPE - 1);
    int tid = threadIdx.x;
    ushort o[8];
    if (c < nvalid[e]) {
        int tok = assign_token[slot];
        const float* src = x + (size_t)tok * DIM + tid * 8;
        float4 a = *(const float4*)src;
        float4 b = *(const float4*)(src + 4);
        o[0] = f2bf(a.x); o[1] = f2bf(a.y); o[2] = f2bf(a.z); o[3] = f2bf(a.w);
        o[4] = f2bf(b.x); o[5] = f2bf(b.y); o[6] = f2bf(b.z); o[7] = f2bf(b.w);
    } else {
#pragma unroll
        for (int j = 0; j < 8; ++j) o[j] = 0;
    }
    *(uint4*)(xg + (size_t)slot * DIM + tid * 8) = *(uint4*)o;
}

// ============ GEMM core (m97 structure): acc = A[128rows]@B[128rows]^T ============
__device__ __forceinline__ void gemm_core(
    const ushort* __restrict__ Ae, const ushort* __restrict__ Be,
    int bm, int bn, int K, int tid, int lane, int wr, int wc,
    ushort* As, ushort* Bs, f32x4 (&acc)[4][4])
{
#pragma unroll
    for (int m = 0; m < 4; ++m)
#pragma unroll
        for (int n = 0; n < 4; ++n)
            acc[m][n] = (f32x4){0.f, 0.f, 0.f, 0.f};

    for (int k0 = 0; k0 < K; k0 += 64) {
#pragma unroll
        for (int j = 0; j < 4; ++j) {
            int c = j * 256 + tid;
            int r = c >> 3, ce = (c & 7) * 8;
            gload16(Ae + (size_t)(bm + r) * K + k0 + ce, &As[(c - lane) * 8]);
        }
#pragma unroll
        for (int j = 0; j < 4; ++j) {
            int c = j * 256 + tid;
            int r = c >> 3, ce = (c & 7) * 8;
            gload16(Be + (size_t)(bn + r) * K + k0 + ce, &Bs[(c - lane) * 8]);
        }
        __syncthreads();
#pragma unroll
        for (int ks = 0; ks < 2; ++ks) {
            int kb = ks * 32 + (lane >> 4) * 8;
            bf16x8 a[4], b[4];
#pragma unroll
            for (int m = 0; m < 4; ++m)
                a[m] = *(const bf16x8*)&As[(wr * 64 + m * 16 + (lane & 15)) * 64 + kb];
#pragma unroll
            for (int n = 0; n < 4; ++n)
                b[n] = *(const bf16x8*)&Bs[(wc * 64 + n * 16 + (lane & 15)) * 64 + kb];
#pragma unroll
            for (int m = 0; m < 4; ++m)
#pragma unroll
                for (int n = 0; n < 4; ++n)
                    acc[m][n] = __builtin_amdgcn_mfma_f32_16x16x32_bf16(a[m], b[n], acc[m][n], 0, 0, 0);
        }
        __syncthreads();
    }
}

// ---------------- merged up-projection GEMM: 1536 blocks ----------------
// ids [0,512): expert w1 -> HA+e*CAPE*HID     [512,1024): expert w3 -> HB
// [1024,1280): shared sw1 -> HA+NE*CAPE*HID   [1280,1536): shared sw3 -> HB+...
__global__ __launch_bounds__(256) void gemm_up(
    const ushort* __restrict__ xg, const ushort* __restrict__ xb,
    const ushort* __restrict__ w1T, const ushort* __restrict__ w3T,
    const ushort* __restrict__ sw1T, const ushort* __restrict__ sw3T,
    ushort* __restrict__ HA, ushort* __restrict__ HB,
    const int* __restrict__ nvalid)
{
    int id = ((int)blockIdx.x & 7) * 192 + ((int)blockIdx.x >> 3); // XCD chunk swizzle
    const ushort *A, *B;
    ushort* O;
    int bm, bn;
    if (id < 1024) {
        int half = id >> 9;
        int rem = id & 511;
        int e = rem >> 5;
        int r2 = rem & 31;
        bm = (r2 >> 3) * 128; bn = (r2 & 7) * 128;
        if (bm >= nvalid[e]) return;
        A = xg + (size_t)e * CAPE * DIM;
        B = (half ? w3T : w1T) + (size_t)e * HID * DIM;
        O = (half ? HB : HA) + (size_t)e * CAPE * HID;
    } else {
        int rem = id - 1024;
        int half = rem >> 8;
        rem &= 255;
        bm = (rem >> 3) * 128; bn = (rem & 7) * 128;
        A = xb;
        B = half ? sw3T : sw1T;
        O = (half ? HB : HA) + (size_t)NE * CAPE * HID;
    }

    __shared__ __align__(16) ushort As[128 * 64];
    __shared__ __align__(16) ushort Bs[128 * 64];
    int tid = threadIdx.x, lane = tid & 63;
    int wr = (tid >> 7) & 1, wc = (tid >> 6) & 1;
    f32x4 acc[4][4];
    gemm_core(A, B, bm, bn, DIM, tid, lane, wr, wc, As, Bs, acc);

    int rbase = bm + wr * 64 + (lane >> 4) * 4;
    int cbase = bn + wc * 64 + (lane & 15);
#pragma unroll
    for (int m = 0; m < 4; ++m)
#pragma unroll
        for (int n = 0; n < 4; ++n) {
            int col = cbase + n * 16;
#pragma unroll
            for (int r = 0; r < 4; ++r)
                O[(size_t)(rbase + m * 16 + r) * HID + col] = f2bf(acc[m][n][r]);
        }
}

// ---------------- silu-mul elementwise: HH = silu(HA)*HB ----------------
__global__ __launch_bounds__(256) void silumul_kernel(
    const ushort* __restrict__ HA, const ushort* __restrict__ HB,
    ushort* __restrict__ HH)
{
    size_t i = ((size_t)blockIdx.x * 256 + threadIdx.x) * 8;
    uint4 av = *(const uint4*)(HA + i);
    uint4 bv = *(const uint4*)(HB + i);
    const ushort* ap = (const ushort*)&av;
    const ushort* bp = (const ushort*)&bv;
    ushort o[8];
#pragma unroll
    for (int j = 0; j < 8; ++j) {
        float g = bf2f(ap[j]);
        float s = g / (1.f + __expf(-g));
        o[j] = f2bf(s * bf2f(bp[j]));
    }
    *(uint4*)(HH + i) = *(uint4*)o;
}

// ---------------- merged down-projection GEMM: 1536 blocks ----------------
// ids [0,1024): expert w2: HH_e @ w2T -> ye (bf16)
// [1024,1536): shared sw2: HH_s @ sw2T -> out (f32, * coef1[row])
__global__ __launch_bounds__(256) void gemm_down(
    const ushort* __restrict__ HH, const ushort* __restrict__ w2T,
    const ushort* __restrict__ sw2T, ushort* __restrict__ ye,
    float* __restrict__ outp, const float* __restrict__ coefo,
    const int* __restrict__ nvalid)
{
    int id = ((int)blockIdx.x & 7) * 192 + ((int)blockIdx.x >> 3);
    const ushort *A, *B;
    int bm, bn, expert;
    ushort* Ob = nullptr;
    if (id < 1024) {
        int e = id >> 6;
        int r2 = id & 63;
        bm = (r2 >> 4) * 128; bn = (r2 & 15) * 128;
        if (bm >= nvalid[e]) return;
        A = HH + (size_t)e * CAPE * HID;
        B = w2T + (size_t)e * DIM * HID;
        Ob = ye + (size_t)e * CAPE * DIM;
        expert = 1;
    } else {
        int rem = id - 1024;
        bm = (rem >> 4) * 128; bn = (rem & 15) * 128;
        A = HH + (size_t)NE * CAPE * HID;
        B = sw2T;
        expert = 0;
    }

    __shared__ __align__(16) ushort As[128 * 64];
    __shared__ __align__(16) ushort Bs[128 * 64];
    int tid = threadIdx.x, lane = tid & 63;
    int wr = (tid >> 7) & 1, wc = (tid >> 6) & 1;
    f32x4 acc[4][4];
    gemm_core(A, B, bm, bn, HID, tid, lane, wr, wc, As, Bs, acc);

    int rbase = bm + wr * 64 + (lane >> 4) * 4;
    int cbase = bn + wc * 64 + (lane & 15);
#pragma unroll
    for (int m = 0; m < 4; ++m)
#pragma unroll
        for (int n = 0; n < 4; ++n) {
            int col = cbase + n * 16;
#pragma unroll
            for (int r = 0; r < 4; ++r) {
                int row = rbase + m * 16 + r;
                float v = acc[m][n][r];
                if (expert) {
                    Ob[(size_t)row * DIM + col] = f2bf(v);
                } else {
                    outp[(size_t)row * DIM + col] = v * coefo[2 * row + 1];
                }
            }
        }
}

// ---------------- final combine: out += coef0*(w0*ye[s0] + w1*ye[s1]) ----------------
__global__ __launch_bounds__(256) void combine_kernel(
    const ushort* __restrict__ ye, const int* __restrict__ sidx,
    const float* __restrict__ swt, const float* __restrict__ coefo,
    float* __restrict__ out)
{
    int idx = blockIdx.x * 256 + threadIdx.x;
    int t = idx >> 9;
    int d = (idx & 511) << 2;
    int s0 = sidx[t * 2], s1 = sidx[t * 2 + 1];
    float c0 = coefo[t * 2];
    float w0 = swt[t * 2] * c0, w1 = swt[t * 2 + 1] * c0;
    float4 v = *(float4*)(out + (size_t)t * DIM + d);
    if (s0 >= 0) {
        const ushort* y = ye + (size_t)s0 * DIM + d;
        v.x += w0 * bf2f(y[0]); v.y += w0 * bf2f(y[1]);
        v.z += w0 * bf2f(y[2]); v.w += w0 * bf2f(y[3]);
    }
    if (s1 >= 0) {
        const ushort* y = ye + (size_t)s1 * DIM + d;
        v.x += w1 * bf2f(y[0]); v.y += w1 * bf2f(y[1]);
        v.z += w1 * bf2f(y[2]); v.w += w1 * bf2f(y[3]);
    }
    *(float4*)(out + (size_t)t * DIM + d) = v;
}

extern "C" void kernel_launch(void* const* d_in, const int* in_sizes, int n_in,
                              void* d_out, int out_size, void* d_ws, size_t ws_size,
                              hipStream_t stream)
{
    const float* x      = (const float*)d_in[0];
    const float* gate_w = (const float*)d_in[1];
    const float* w1     = (const float*)d_in[2];
    const float* w3     = (const float*)d_in[3];
    const float* w2     = (const float*)d_in[4];
    const float* sw1    = (const float*)d_in[5];
    const float* sw3    = (const float*)d_in[6];
    const float* sw2    = (const float*)d_in[7];
    const float* coef_w = (const float*)d_in[8];
    const float* coef_b = (const float*)d_in[9];
    float* out = (float*)d_out;

    char* ws = (char*)d_ws;
    size_t off = 0;
    auto alloc = [&](size_t bytes) -> void* {
        void* p = ws + off;
        off += (bytes + 255) & ~(size_t)255;
        return p;
    };
    float*  probs_sum    = (float*)alloc(NE * 4);
    int*    nvalid       = (int*)alloc(NE * 4);
    int*    topidx       = (int*)alloc((size_t)T_TOK * 2 * 4);
    float*  gatesw       = (float*)alloc((size_t)T_TOK * 2 * 4);
    float*  coefo        = (float*)alloc((size_t)T_TOK * 2 * 4);
    int*    sidx         = (int*)alloc((size_t)T_TOK * 2 * 4);
    float*  swt          = (float*)alloc((size_t)T_TOK * 2 * 4);
    int*    assign_token = (int*)alloc((size_t)NE * CAPE * 4);
    float*  logits       = (float*)alloc((size_t)T_TOK * 18 * 4);
    ushort* w1T  = (ushort*)alloc((size_t)NE * HID * DIM * 2);
    ushort* w3T  = (ushort*)alloc((size_t)NE * HID * DIM * 2);
    ushort* w2T  = (ushort*)alloc((size_t)NE * DIM * HID * 2);
    ushort* sw1T = (ushort*)alloc((size_t)HID * DIM * 2);
    ushort* sw3T = (ushort*)alloc((size_t)HID * DIM * 2);
    ushort* sw2T = (ushort*)alloc((size_t)DIM * HID * 2);
    ushort* xb   = (ushort*)alloc((size_t)T_TOK * DIM * 2);
    ushort* xg   = (ushort*)alloc((size_t)NE * CAPE * DIM * 2);
    size_t HROWS = (size_t)NE * CAPE + T_TOK;
    ushort* HA   = (ushort*)alloc(HROWS * HID * 2);
    ushort* HB   = (ushort*)alloc(HROWS * HID * 2);
    ushort* HH   = (ushort*)alloc(HROWS * HID * 2);
    ushort* ye   = (ushort*)alloc((size_t)NE * CAPE * DIM * 2);

    hipMemsetAsync(probs_sum, 0, NE * 4, stream);
    logits_kernel<<<T_TOK / 4, 256, 0, stream>>>(x, gate_w, coef_w, logits);
    finish_kernel<<<T_TOK / 256, 256, 0, stream>>>(logits, coef_b,
                                                   topidx, gatesw, coefo, probs_sum);
    scan_kernel<<<1, 256, 0, stream>>>(topidx, gatesw, probs_sum,
                                       sidx, swt, assign_token, nvalid,
                                       out + (size_t)T_TOK * DIM);

    // weight transposes + x convert + token gather
    transpose_kernel<<<dim3(DIM/64, HID/64, NE), 256, 0, stream>>>(w1, w1T, DIM, HID, (size_t)DIM*HID, (size_t)HID*DIM);
    transpose_kernel<<<dim3(DIM/64, HID/64, NE), 256, 0, stream>>>(w3, w3T, DIM, HID, (size_t)DIM*HID, (size_t)HID*DIM);
    transpose_kernel<<<dim3(HID/64, DIM/64, NE), 256, 0, stream>>>(w2, w2T, HID, DIM, (size_t)HID*DIM, (size_t)DIM*HID);
    transpose_kernel<<<dim3(DIM/64, HID/64, 1), 256, 0, stream>>>(sw1, sw1T, DIM, HID, 0, 0);
    transpose_kernel<<<dim3(DIM/64, HID/64, 1), 256, 0, stream>>>(sw3, sw3T, DIM, HID, 0, 0);
    transpose_kernel<<<dim3(HID/64, DIM/64, 1), 256, 0, stream>>>(sw2, sw2T, HID, DIM, 0, 0);
    convert_kernel<<<(T_TOK * DIM) / (256 * 8), 256, 0, stream>>>(x, xb);
    gather_kernel<<<NE * CAPE, 256, 0, stream>>>(x, assign_token, nvalid, xg);

    // merged up-projection (expert w1/w3 + shared sw1/sw3)
    gemm_up<<<1536, 256, 0, stream>>>(xg, xb, w1T, w3T, sw1T, sw3T, HA, HB, nvalid);
    // silu-mul over all rows
    silumul_kernel<<<(int)(HROWS * HID / (256 * 8)), 256, 0, stream>>>(HA, HB, HH);
    // merged down-projection (expert w2 -> ye bf16, shared sw2 -> out f32)
    gemm_down<<<1536, 256, 0, stream>>>(HH, w2T, sw2T, ye, out, coefo, nvalid);

    combine_kernel<<<(T_TOK * (DIM / 4)) / 256, 256, 0, stream>>>(ye, sidx, swt, coefo, out);
}

// Round 6
// 486.852 us; speedup vs baseline: 1.2205x; 1.1467x over previous
//
#include <hip/hip_runtime.h>
#include <hip/hip_bf16.h>
#include <stdint.h>

#define T_TOK 4096
#define DIM   2048
#define HID   1024
#define NE    16
#define CAPE  512

typedef __bf16 bf16x8 __attribute__((ext_vector_type(8)));
typedef float  f32x4  __attribute__((ext_vector_type(4)));

__device__ __forceinline__ ushort f2bf(float f) {
    union { float f; uint32_t u; } v; v.f = f;
    uint32_t r = (v.u + 0x7FFFu + ((v.u >> 16) & 1u)) >> 16;
    return (ushort)r;
}
__device__ __forceinline__ float bf2f(ushort u) {
    union { uint32_t u; float f; } v; v.u = (uint32_t)u << 16; return v.f;
}
__device__ __forceinline__ void gload16(const void* g, void* lds) {
    __builtin_amdgcn_global_load_lds(
        (const __attribute__((address_space(1))) uint32_t*)g,
        (__attribute__((address_space(3))) uint32_t*)lds, 16, 0, 0);
}

// ---------------- logits: one wave per token, 18 outputs ----------------
__global__ __launch_bounds__(256) void logits_kernel(
    const float* __restrict__ x, const float* __restrict__ gate_w,
    const float* __restrict__ coef_w, float* __restrict__ logits)
{
    int t = blockIdx.x * 4 + (threadIdx.x >> 6);
    int lane = threadIdx.x & 63;
    const float* xr = x + (size_t)t * DIM;
    float acc[18];
#pragma unroll
    for (int o = 0; o < 18; ++o) acc[o] = 0.f;
    for (int d = lane; d < DIM; d += 64) {
        float xv = xr[d];
        const float* gw = gate_w + (size_t)d * NE;
#pragma unroll
        for (int o = 0; o < NE; ++o) acc[o] += xv * gw[o];
        acc[16] += xv * coef_w[d * 2 + 0];
        acc[17] += xv * coef_w[d * 2 + 1];
    }
#pragma unroll
    for (int off = 32; off > 0; off >>= 1) {
#pragma unroll
        for (int o = 0; o < 18; ++o) acc[o] += __shfl_down(acc[o], off, 64);
    }
    if (lane == 0) {
#pragma unroll
        for (int o = 0; o < 18; ++o) logits[(size_t)t * 18 + o] = acc[o];
    }
}

// ---------------- finish: one thread per token ----------------
__global__ __launch_bounds__(256) void finish_kernel(
    const float* __restrict__ logits, const float* __restrict__ coef_b,
    int* __restrict__ topidx, float* __restrict__ gatesw,
    float* __restrict__ coefo, float* __restrict__ probs_sum)
{
    __shared__ float wred[4][NE];
    int t = blockIdx.x * 256 + threadIdx.x;
    float lg[18];
#pragma unroll
    for (int o = 0; o < 18; ++o) lg[o] = logits[(size_t)t * 18 + o];
    float p[NE];
    float m = lg[0];
#pragma unroll
    for (int e = 1; e < NE; ++e) m = fmaxf(m, lg[e]);
    float ssum = 0.f;
#pragma unroll
    for (int e = 0; e < NE; ++e) { p[e] = expf(lg[e] - m); ssum += p[e]; }
    float inv = 1.f / ssum;
#pragma unroll
    for (int e = 0; e < NE; ++e) p[e] *= inv;
    int i1 = 0;
#pragma unroll
    for (int e = 1; e < NE; ++e) if (p[e] > p[i1]) i1 = e;
    int i2 = -1;
#pragma unroll
    for (int e = 0; e < NE; ++e) { if (e == i1) continue; if (i2 < 0 || p[e] > p[i2]) i2 = e; }
    float g0 = p[i1], g1 = p[i2], gs = g0 + g1;
    topidx[t * 2 + 0] = i1; topidx[t * 2 + 1] = i2;
    gatesw[t * 2 + 0] = g0 / gs; gatesw[t * 2 + 1] = g1 / gs;
    float c0 = lg[16] + coef_b[0], c1 = lg[17] + coef_b[1];
    float cm = fmaxf(c0, c1);
    float e0 = expf(c0 - cm), e1 = expf(c1 - cm);
    float cs = e0 + e1;
    coefo[t * 2 + 0] = e0 / cs; coefo[t * 2 + 1] = e1 / cs;

    float r[NE];
#pragma unroll
    for (int e = 0; e < NE; ++e) r[e] = p[e];
#pragma unroll
    for (int off = 32; off > 0; off >>= 1) {
#pragma unroll
        for (int e = 0; e < NE; ++e) r[e] += __shfl_down(r[e], off, 64);
    }
    int wv = threadIdx.x >> 6, ln = threadIdx.x & 63;
    if (ln == 0) {
#pragma unroll
        for (int e = 0; e < NE; ++e) wred[wv][e] = r[e];
    }
    __syncthreads();
    if (threadIdx.x < NE) {
        float s = wred[0][threadIdx.x] + wred[1][threadIdx.x]
                + wred[2][threadIdx.x] + wred[3][threadIdx.x];
        atomicAdd(&probs_sum[threadIdx.x], s);
    }
}

// ---------------- sequential capacity scan: single block ----------------
__global__ __launch_bounds__(256) void scan_kernel(
    const int* __restrict__ topidx, const float* __restrict__ gatesw,
    const float* __restrict__ probs_sum,
    int* __restrict__ sidx, float* __restrict__ swt,
    int* __restrict__ assign_token, int* __restrict__ nvalid,
    float* __restrict__ out_tail)
{
    __shared__ int run[NE];
    __shared__ int whist[4][NE];
    __shared__ int cnt0[NE];
    __shared__ int base[NE];
    int tid = threadIdx.x, wv = tid >> 6, ln = tid & 63;
    unsigned long long ltmask = (1ull << ln) - 1ull;

    for (int kk = 0; kk < 2; ++kk) {
        if (tid < NE) {
            if (kk == 0) base[tid] = 0;
            else { cnt0[tid] = run[tid]; base[tid] = run[tid]; }
            run[tid] = 0;
        }
        __syncthreads();
        for (int c = 0; c < T_TOK; c += 256) {
            int t = c + tid;
            int e = topidx[t * 2 + kk];
            int within = 0;
            for (int ee = 0; ee < NE; ++ee) {
                unsigned long long b = __ballot(e == ee);
                if (ee == e) within = __popcll(b & ltmask);
                if (ln == 0) whist[wv][ee] = __popcll(b);
            }
            __syncthreads();
            int cross = 0;
            for (int w = 0; w < wv; ++w) cross += whist[w][e];
            int loc = run[e] + cross + within;
            int pos = base[e] + loc;
            bool keep = pos < CAPE;
            sidx[t * 2 + kk] = keep ? (e * CAPE + pos) : -1;
            swt[t * 2 + kk] = keep ? gatesw[t * 2 + kk] : 0.f;
            if (keep) assign_token[e * CAPE + pos] = t;
            __syncthreads();
            if (tid < NE) {
                run[tid] += whist[0][tid] + whist[1][tid] + whist[2][tid] + whist[3][tid];
            }
            __syncthreads();
        }
    }
    if (tid < NE) {
        int c0v = cnt0[tid], c1v = run[tid];
        nvalid[tid] = min(CAPE, c0v + c1v);
        out_tail[1 + tid] = (float)(c0v + c1v);
    }
    __syncthreads();
    if (tid == 0) {
        float la = 0.f;
        for (int e = 0; e < NE; ++e)
            la += (probs_sum[e] / (float)T_TOK) * ((float)cnt0[e] / (float)T_TOK);
        out_tail[0] = la * (float)NE;
    }
}

// ---------------- transpose + convert: f32 [R][C] -> bf16 [C][R] ----------------
__global__ __launch_bounds__(256) void transpose_kernel(
    const float* __restrict__ in, ushort* __restrict__ out,
    int R, int C, size_t IEs, size_t OEs)
{
    __shared__ __align__(16) ushort tile[64][72];
    int e = blockIdx.z;
    const float* ie = in + (size_t)e * IEs;
    ushort* oe = out + (size_t)e * OEs;
    int r0 = blockIdx.x * 64, c0 = blockIdx.y * 64;
    int tid = threadIdx.x;
    int rr = tid >> 4, cc = (tid & 15) * 4;
#pragma unroll
    for (int i = 0; i < 4; ++i) {
        int r = i * 16 + rr;
        float4 v = *(const float4*)(ie + (size_t)(r0 + r) * C + c0 + cc);
        tile[cc + 0][r] = f2bf(v.x);
        tile[cc + 1][r] = f2bf(v.y);
        tile[cc + 2][r] = f2bf(v.z);
        tile[cc + 3][r] = f2bf(v.w);
    }
    __syncthreads();
    int oc = tid >> 3, orr = (tid & 7) * 8;
#pragma unroll
    for (int i = 0; i < 2; ++i) {
        int c = i * 32 + oc;
        uint4 v = *(const uint4*)&tile[c][orr];
        *(uint4*)(oe + (size_t)(c0 + c) * R + r0 + orr) = v;
    }
}

// ---------------- f32 -> bf16 convert (contiguous) ----------------
__global__ __launch_bounds__(256) void convert_kernel(
    const float* __restrict__ in, ushort* __restrict__ out)
{
    int i = (blockIdx.x * 256 + threadIdx.x) * 8;
    float4 a = *(const float4*)(in + i);
    float4 b = *(const float4*)(in + i + 4);
    ushort o[8];
    o[0] = f2bf(a.x); o[1] = f2bf(a.y); o[2] = f2bf(a.z); o[3] = f2bf(a.w);
    o[4] = f2bf(b.x); o[5] = f2bf(b.y); o[6] = f2bf(b.z); o[7] = f2bf(b.w);
    *(uint4*)(out + i) = *(uint4*)o;
}

// ---------------- gather tokens -> dense bf16 [E*CAPE][DIM], zero-fill ----------------
__global__ __launch_bounds__(256) void gather_kernel(
    const float* __restrict__ x, const int* __restrict__ assign_token,
    const int* __restrict__ nvalid, ushort* __restrict__ xg)
{
    int slot = blockIdx.x;
    int e = slot >> 9, c = slot & (CAPE - 1);
    int tid = threadIdx.x;
    ushort o[8];
    if (c < nvalid[e]) {
        int tok = assign_token[slot];
        const float* src = x + (size_t)tok * DIM + tid * 8;
        float4 a = *(const float4*)src;
        float4 b = *(const float4*)(src + 4);
        o[0] = f2bf(a.x); o[1] = f2bf(a.y); o[2] = f2bf(a.z); o[3] = f2bf(a.w);
        o[4] = f2bf(b.x); o[5] = f2bf(b.y); o[6] = f2bf(b.z); o[7] = f2bf(b.w);
    } else {
#pragma unroll
        for (int j = 0; j < 8; ++j) o[j] = 0;
    }
    *(uint4*)(xg + (size_t)slot * DIM + tid * 8) = *(uint4*)o;
}

// ================= 256x256 8-phase MFMA GEMM (T2+T3+T4+T5) =================
// LDS layout (bytes): dbuf d: A at d*65536 (256 rows x 128B), B at d*65536+32768.
// Swizzle (both sides): colbyte ^= (row&7)<<4 within each 128B row.
#define LDSA(d) ((d) * 65536)
#define LDSB(d) ((d) * 65536 + 32768)

// stage one 128-row x 64-col half-tile: linear LDS dest, inverse-swizzled source
__device__ __forceinline__ void stage_half(
    const ushort* __restrict__ G, int gstride, int grow0, int k0,
    char* region, int tid)
{
#pragma unroll
    for (int q = 0; q < 2; ++q) {
        int c = q * 512 + tid;
        int row = c >> 3;
        int cb = (c & 7) << 4;
        int scb = cb ^ ((row & 7) << 4);
        const ushort* src = G + (size_t)(grow0 + row) * gstride + k0 + (scb >> 1);
        gload16(src, region + ((c - (tid & 63)) << 4));
    }
}

__device__ __forceinline__ bf16x8 ldfrag(const char* lds, int region, int row, int cb) {
    return *(const bf16x8*)(lds + region + row * 128 + (cb ^ ((row & 7) << 4)));
}

// core: acc[8][4] (per-wave 128x64 output), A,B row-major [rows][K], C = A@B^T tile
__device__ __forceinline__ void gemm8_core(
    const ushort* __restrict__ A, const ushort* __restrict__ B,
    int bm, int bn, int K, char* lds, f32x4 (&acc)[8][4], int tid)
{
    int lane = tid & 63;
    int wid = tid >> 6;
    int wrow = wid >> 2, wcol = wid & 3;
    int l15 = lane & 15, hi = lane >> 4;

#pragma unroll
    for (int m = 0; m < 8; ++m)
#pragma unroll
        for (int n = 0; n < 4; ++n)
            acc[m][n] = (f32x4){0.f, 0.f, 0.f, 0.f};

    int nj = K >> 7;  // K/128: iterations of 2 K-tiles

    // prologue: d0 full (tile0) + d1.B (tile1)
    stage_half(A, K, bm,       0, lds + LDSA(0),         tid);
    stage_half(A, K, bm + 128, 0, lds + LDSA(0) + 16384, tid);
    stage_half(B, K, bn,       0, lds + LDSB(0),         tid);
    stage_half(B, K, bn + 128, 0, lds + LDSB(0) + 16384, tid);
    stage_half(B, K, bn,      64, lds + LDSB(1),         tid);
    stage_half(B, K, bn + 128,64, lds + LDSB(1) + 16384, tid);
    asm volatile("s_waitcnt vmcnt(4)" ::: "memory");
    __builtin_amdgcn_s_barrier();
    __builtin_amdgcn_sched_barrier(0);

    for (int j = 0; j < nj; ++j) {
        int k1 = (2 * j + 1) << 6, k2 = (2 * j + 2) << 6, k3 = (2 * j + 3) << 6;
        bool st = (j < nj - 1);
#pragma unroll
        for (int d = 0; d < 2; ++d) {  // d=0: phases 1-4 (dbuf0); d=1: phases 5-8 (dbuf1)
            bf16x8 bf[4][2];
#pragma unroll
            for (int p = 0; p < 4; ++p) {
                if (p == 0) {
#pragma unroll
                    for (int n = 0; n < 4; ++n)
#pragma unroll
                        for (int ks = 0; ks < 2; ++ks)
                            bf[n][ks] = ldfrag(lds, LDSB(d), wcol * 64 + n * 16 + l15, ks * 64 + hi * 16);
                }
                bf16x8 af[2][2];
#pragma unroll
                for (int i = 0; i < 2; ++i)
#pragma unroll
                    for (int ks = 0; ks < 2; ++ks)
                        af[i][ks] = ldfrag(lds, LDSA(d), wrow * 128 + (2 * p + i) * 16 + l15, ks * 64 + hi * 16);
                // staging schedule (WAR-safe vs phase reads)
                if (d == 0) {
                    if (p == 0)      stage_half(A, K, bm,       k1, lds + LDSA(1),         tid);
                    else if (p == 1) stage_half(A, K, bm + 128, k1, lds + LDSA(1) + 16384, tid);
                    else if (p == 2) { if (st) stage_half(B, K, bn,       k2, lds + LDSB(0),         tid); }
                    else             { if (st) stage_half(B, K, bn + 128, k2, lds + LDSB(0) + 16384, tid); }
                } else {
                    if (st) {
                        if (p == 0)      stage_half(A, K, bm,       k2, lds + LDSA(0),         tid);
                        else if (p == 1) stage_half(A, K, bm + 128, k2, lds + LDSA(0) + 16384, tid);
                        else if (p == 2) stage_half(B, K, bn,       k3, lds + LDSB(1),         tid);
                        else             stage_half(B, K, bn + 128, k3, lds + LDSB(1) + 16384, tid);
                    }
                }
                __builtin_amdgcn_s_barrier();
                if (p == 3) {
                    if (d == 0) {
                        if (st) asm volatile("s_waitcnt vmcnt(4)" ::: "memory");
                        else    asm volatile("s_waitcnt vmcnt(0)" ::: "memory");
                    } else if (st) {
                        asm volatile("s_waitcnt vmcnt(4)" ::: "memory");
                    }
                }
                asm volatile("s_waitcnt lgkmcnt(0)" ::: "memory");
                __builtin_amdgcn_sched_barrier(0);
                __builtin_amdgcn_s_setprio(1);
#pragma unroll
                for (int i = 0; i < 2; ++i)
#pragma unroll
                    for (int n = 0; n < 4; ++n)
#pragma unroll
                        for (int ks = 0; ks < 2; ++ks)
                            acc[2 * p + i][n] = __builtin_amdgcn_mfma_f32_16x16x32_bf16(
                                af[i][ks], bf[n][ks], acc[2 * p + i][n], 0, 0, 0);
                __builtin_amdgcn_s_setprio(0);
                __builtin_amdgcn_s_barrier();
                __builtin_amdgcn_sched_barrier(0);
            }
        }
    }
}

// merged up-projection: 384 blocks. ids [0,256): expert w1/w3; [256,384): shared
__global__ __launch_bounds__(512, 2) void gemm8_up(
    const ushort* __restrict__ xg, const ushort* __restrict__ xb,
    const ushort* __restrict__ w1T, const ushort* __restrict__ w3T,
    const ushort* __restrict__ sw1T, const ushort* __restrict__ sw3T,
    ushort* __restrict__ HA, ushort* __restrict__ HB,
    const int* __restrict__ nvalid)
{
    __shared__ __align__(16) char lds[131072];
    int b = blockIdx.x;
    int id = (b & 7) * 48 + (b >> 3);
    const ushort *A, *B;
    ushort* O;
    int bm, bn;
    if (id < 256) {
        int e = id >> 4, rem = id & 15;
        int half = rem >> 3, mt = (rem >> 2) & 1, nt = rem & 3;
        bm = mt * 256; bn = nt * 256;
        if (bm >= nvalid[e]) return;
        A = xg + (size_t)e * CAPE * DIM;
        B = (half ? w3T : w1T) + (size_t)e * HID * DIM;
        O = (half ? HB : HA) + (size_t)e * CAPE * HID;
    } else {
        int rem = id - 256;
        int half = rem >> 6; rem &= 63;
        int mt = rem >> 2, nt = rem & 3;
        bm = mt * 256; bn = nt * 256;
        A = xb; B = half ? sw3T : sw1T;
        O = (half ? HB : HA) + (size_t)NE * CAPE * HID;
    }
    int tid = threadIdx.x;
    f32x4 acc[8][4];
    gemm8_core(A, B, bm, bn, DIM, lds, acc, tid);

    int lane = tid & 63, wid = tid >> 6;
    int wrow = wid >> 2, wcol = wid & 3;
    int rbase = bm + wrow * 128 + (lane >> 4) * 4;
    int cbase = bn + wcol * 64 + (lane & 15);
#pragma unroll
    for (int m = 0; m < 8; ++m)
#pragma unroll
        for (int n = 0; n < 4; ++n) {
            int col = cbase + n * 16;
#pragma unroll
            for (int r = 0; r < 4; ++r)
                O[(size_t)(rbase + m * 16 + r) * HID + col] = f2bf(acc[m][n][r]);
        }
}

// merged down-projection: 384 blocks. ids [0,256): expert w2 -> ye bf16;
// [256,384): shared sw2 -> out f32 * coef1[row]
__global__ __launch_bounds__(512, 2) void gemm8_down(
    const ushort* __restrict__ HH, const ushort* __restrict__ w2T,
    const ushort* __restrict__ sw2T, ushort* __restrict__ ye,
    float* __restrict__ outp, const float* __restrict__ coefo,
    const int* __restrict__ nvalid)
{
    __shared__ __align__(16) char lds[131072];
    int b = blockIdx.x;
    int id = (b & 7) * 48 + (b >> 3);
    const ushort *A, *B;
    int bm, bn, expert;
    ushort* Ob = nullptr;
    if (id < 256) {
        int e = id >> 4, rem = id & 15;
        int mt = rem >> 3, nt = rem & 7;
        bm = mt * 256; bn = nt * 256;
        if (bm >= nvalid[e]) return;
        A = HH + (size_t)e * CAPE * HID;
        B = w2T + (size_t)e * DIM * HID;
        Ob = ye + (size_t)e * CAPE * DIM;
        expert = 1;
    } else {
        int rem = id - 256;
        int mt = rem >> 3, nt = rem & 7;
        bm = mt * 256; bn = nt * 256;
        A = HH + (size_t)NE * CAPE * HID;
        B = sw2T;
        expert = 0;
    }
    int tid = threadIdx.x;
    f32x4 acc[8][4];
    gemm8_core(A, B, bm, bn, HID, lds, acc, tid);

    int lane = tid & 63, wid = tid >> 6;
    int wrow = wid >> 2, wcol = wid & 3;
    int rbase = bm + wrow * 128 + (lane >> 4) * 4;
    int cbase = bn + wcol * 64 + (lane & 15);
#pragma unroll
    for (int m = 0; m < 8; ++m)
#pragma unroll
        for (int n = 0; n < 4; ++n) {
            int col = cbase + n * 16;
#pragma unroll
            for (int r = 0; r < 4; ++r) {
                int row = rbase + m * 16 + r;
                float v = acc[m][n][r];
                if (expert) Ob[(size_t)row * DIM + col] = f2bf(v);
                else        outp[(size_t)row * DIM + col] = v * coefo[2 * row + 1];
            }
        }
}

// ---------------- silu-mul elementwise: HH = silu(HA)*HB ----------------
__global__ __launch_bounds__(256) void silumul_kernel(
    const ushort* __restrict__ HA, const ushort* __restrict__ HB,
    ushort* __restrict__ HH)
{
    size_t i = ((size_t)blockIdx.x * 256 + threadIdx.x) * 8;
    uint4 av = *(const uint4*)(HA + i);
    uint4 bv = *(const uint4*)(HB + i);
    const ushort* ap = (const ushort*)&av;
    const ushort* bp = (const ushort*)&bv;
    ushort o[8];
#pragma unroll
    for (int j = 0; j < 8; ++j) {
        float g = bf2f(ap[j]);
        float s = g / (1.f + __expf(-g));
        o[j] = f2bf(s * bf2f(bp[j]));
    }
    *(uint4*)(HH + i) = *(uint4*)o;
}

// ---------------- final combine: out += coef0*(w0*ye[s0] + w1*ye[s1]) ----------------
__global__ __launch_bounds__(256) void combine_kernel(
    const ushort* __restrict__ ye, const int* __restrict__ sidx,
    const float* __restrict__ swt, const float* __restrict__ coefo,
    float* __restrict__ out)
{
    int idx = blockIdx.x * 256 + threadIdx.x;
    int t = idx >> 9;
    int d = (idx & 511) << 2;
    int s0 = sidx[t * 2], s1 = sidx[t * 2 + 1];
    float c0 = coefo[t * 2];
    float w0 = swt[t * 2] * c0, w1 = swt[t * 2 + 1] * c0;
    float4 v = *(float4*)(out + (size_t)t * DIM + d);
    if (s0 >= 0) {
        const ushort* y = ye + (size_t)s0 * DIM + d;
        v.x += w0 * bf2f(y[0]); v.y += w0 * bf2f(y[1]);
        v.z += w0 * bf2f(y[2]); v.w += w0 * bf2f(y[3]);
    }
    if (s1 >= 0) {
        const ushort* y = ye + (size_t)s1 * DIM + d;
        v.x += w1 * bf2f(y[0]); v.y += w1 * bf2f(y[1]);
        v.z += w1 * bf2f(y[2]); v.w += w1 * bf2f(y[3]);
    }
    *(float4*)(out + (size_t)t * DIM + d) = v;
}

extern "C" void kernel_launch(void* const* d_in, const int* in_sizes, int n_in,
                              void* d_out, int out_size, void* d_ws, size_t ws_size,
                              hipStream_t stream)
{
    const float* x      = (const float*)d_in[0];
    const float* gate_w = (const float*)d_in[1];
    const float* w1     = (const float*)d_in[2];
    const float* w3     = (const float*)d_in[3];
    const float* w2     = (const float*)d_in[4];
    const float* sw1    = (const float*)d_in[5];
    const float* sw3    = (const float*)d_in[6];
    const float* sw2    = (const float*)d_in[7];
    const float* coef_w = (const float*)d_in[8];
    const float* coef_b = (const float*)d_in[9];
    float* out = (float*)d_out;

    char* ws = (char*)d_ws;
    size_t off = 0;
    auto alloc = [&](size_t bytes) -> void* {
        void* p = ws + off;
        off += (bytes + 255) & ~(size_t)255;
        return p;
    };
    float*  probs_sum    = (float*)alloc(NE * 4);
    int*    nvalid       = (int*)alloc(NE * 4);
    int*    topidx       = (int*)alloc((size_t)T_TOK * 2 * 4);
    float*  gatesw       = (float*)alloc((size_t)T_TOK * 2 * 4);
    float*  coefo        = (float*)alloc((size_t)T_TOK * 2 * 4);
    int*    sidx         = (int*)alloc((size_t)T_TOK * 2 * 4);
    float*  swt          = (float*)alloc((size_t)T_TOK * 2 * 4);
    int*    assign_token = (int*)alloc((size_t)NE * CAPE * 4);
    float*  logits       = (float*)alloc((size_t)T_TOK * 18 * 4);
    ushort* w1T  = (ushort*)alloc((size_t)NE * HID * DIM * 2);
    ushort* w3T  = (ushort*)alloc((size_t)NE * HID * DIM * 2);
    ushort* w2T  = (ushort*)alloc((size_t)NE * DIM * HID * 2);
    ushort* sw1T = (ushort*)alloc((size_t)HID * DIM * 2);
    ushort* sw3T = (ushort*)alloc((size_t)HID * DIM * 2);
    ushort* sw2T = (ushort*)alloc((size_t)DIM * HID * 2);
    ushort* xb   = (ushort*)alloc((size_t)T_TOK * DIM * 2);
    ushort* xg   = (ushort*)alloc((size_t)NE * CAPE * DIM * 2);
    size_t HROWS = (size_t)NE * CAPE + T_TOK;
    ushort* HA   = (ushort*)alloc(HROWS * HID * 2);
    ushort* HB   = (ushort*)alloc(HROWS * HID * 2);
    ushort* HH   = (ushort*)alloc(HROWS * HID * 2);
    ushort* ye   = (ushort*)alloc((size_t)NE * CAPE * DIM * 2);

    hipMemsetAsync(probs_sum, 0, NE * 4, stream);
    logits_kernel<<<T_TOK / 4, 256, 0, stream>>>(x, gate_w, coef_w, logits);
    finish_kernel<<<T_TOK / 256, 256, 0, stream>>>(logits, coef_b,
                                                   topidx, gatesw, coefo, probs_sum);
    scan_kernel<<<1, 256, 0, stream>>>(topidx, gatesw, probs_sum,
                                       sidx, swt, assign_token, nvalid,
                                       out + (size_t)T_TOK * DIM);

    // weight transposes + x convert + token gather
    transpose_kernel<<<dim3(DIM/64, HID/64, NE), 256, 0, stream>>>(w1, w1T, DIM, HID, (size_t)DIM*HID, (size_t)HID*DIM);
    transpose_kernel<<<dim3(DIM/64, HID/64, NE), 256, 0, stream>>>(w3, w3T, DIM, HID, (size_t)DIM*HID, (size_t)HID*DIM);
    transpose_kernel<<<dim3(HID/64, DIM/64, NE), 256, 0, stream>>>(w2, w2T, HID, DIM, (size_t)HID*DIM, (size_t)DIM*HID);
    transpose_kernel<<<dim3(DIM/64, HID/64, 1), 256, 0, stream>>>(sw1, sw1T, DIM, HID, 0, 0);
    transpose_kernel<<<dim3(DIM/64, HID/64, 1), 256, 0, stream>>>(sw3, sw3T, DIM, HID, 0, 0);
    transpose_kernel<<<dim3(HID/64, DIM/64, 1), 256, 0, stream>>>(sw2, sw2T, HID, DIM, 0, 0);
    convert_kernel<<<(T_TOK * DIM) / (256 * 8), 256, 0, stream>>>(x, xb);
    gather_kernel<<<NE * CAPE, 256, 0, stream>>>(x, assign_token, nvalid, xg);

    // merged 8-phase up-projection (expert w1/w3 + shared sw1/sw3)
    gemm8_up<<<384, 512, 0, stream>>>(xg, xb, w1T, w3T, sw1T, sw3T, HA, HB, nvalid);
    // silu-mul over all rows
    silumul_kernel<<<(int)(HROWS * HID / (256 * 8)), 256, 0, stream>>>(HA, HB, HH);
    // merged 8-phase down-projection (expert w2 -> ye bf16, shared sw2 -> out f32)
    gemm8_down<<<384, 512, 0, stream>>>(HH, w2T, sw2T, ye, out, coefo, nvalid);

    combine_kernel<<<(T_TOK * (DIM / 4)) / 256, 256, 0, stream>>>(ye, sidx, swt, coefo, out);
}